// Round 7
// baseline (124.239 us; speedup 1.0000x reference)
//
#include <hip/hip_runtime.h>
#include <hip/hip_bf16.h>
#include <math.h>

#define HDIM 100
#define NFACT 262144
#define FPB   128             // facts per block
#define NBLK  2048            // NFACT / FPB
#define NTHREADS 448          // 7 waves; wave w owns j-tile jt=w

// K packed to 208: k in [0,104) -> |f - oc| (valid k<100), k in [104,208) -> |f - m|.
// kc tiles of 32: 7 tiles cover 224; kglob in [208,224) dead (B zero, z zeroed).
#define KDIM 208
#define NJT  7
#define NKC  7
#define NBFRAG (NJT * NKC * 64)   // 3136 uint4

#define ZSTRIDE 232           // bf16 elems/row: 464 B = 29*16 (b128-aligned rows),
                              // 116 dwords -> r*116%32 spreads banks; b128 reads conflict-free

using short8 = __attribute__((ext_vector_type(8))) short;
using f32x4  = __attribute__((ext_vector_type(4))) float;

// ---------------- ws float-offset layout ----------------
#define WS_B     0                    // 12544 floats (B fragments, bf16 bits)
#define WS_SP    12544                // NBLK partial softmax denoms
#define WS_PC    (WS_SP + NBLK)      // NBLK*100 partial weighted sums [block][h]

__device__ __forceinline__ unsigned short f2bf(float x) {
    unsigned u = __builtin_bit_cast(unsigned, x);
    u += 0x7FFFu + ((u >> 16) & 1u);          // RNE round to bf16
    return (unsigned short)(u >> 16);
}

__device__ __forceinline__ float tanh_fast(float x) {
    float e = __expf(2.0f * x);
    return 1.0f - 2.0f / (1.0f + e);
}

// ---- Precompute W1 as MFMA B-fragments (bf16), frag order [jt][kc][lane][8] ----
// B[k][j]: j = jt*16 + (lane&15); k = kc*32 + (lane>>4)*8 + e.
__global__ __launch_bounds__(256) void k_prep_b(const float* __restrict__ W1,
                                                float* __restrict__ ws) {
    int t = blockIdx.x * 256 + threadIdx.x;
    if (t >= NBFRAG) return;
    int lane = t & 63;
    int kc = (t >> 6) % NKC;
    int jt = t / (NKC * 64);
    int g = lane >> 4, r = lane & 15;
    int j = jt * 16 + r;
    unsigned short v[8];
    #pragma unroll
    for (int e = 0; e < 8; e++) {
        int kglob = kc * 32 + g * 8 + e;
        int half = (kglob >= 104) ? 1 : 0;
        int koff = kglob - half * 104;
        float x = 0.f;
        if (kglob < KDIM && j < HDIM && koff < HDIM)
            x = W1[j * 200 + half * HDIM + koff];
        v[e] = f2bf(x);
    }
    uint4 d;
    d.x = (unsigned)v[0] | ((unsigned)v[1] << 16);
    d.y = (unsigned)v[2] | ((unsigned)v[3] << 16);
    d.z = (unsigned)v[4] | ((unsigned)v[5] << 16);
    d.w = (unsigned)v[6] | ((unsigned)v[7] << 16);
    ((uint4*)(ws + WS_B))[t] = d;
}

// Fused: z-tile built ONCE at staging (bf16, MFMA-ready) -> per-wave j-slice MFMA
// (B fixed in 28 VGPRs) -> softmax partials -> pooling (fe re-read, L2-hot).
__global__ __launch_bounds__(NTHREADS, 4) void k_logits(
        const float* __restrict__ fe,
        const float* __restrict__ oc,
        const float* __restrict__ mvec,
        const float* __restrict__ b1,
        const float* __restrict__ W2,
        float* __restrict__ ws) {
    __shared__ unsigned short ztile[FPB * ZSTRIDE];   // 59392 B
    __shared__ float gvp[NJT][FPB];                   // per-jt partial g
    __shared__ float wls[FPB];
    __shared__ float sred[2];
    __shared__ float poolbuf[4][HDIM];

    int t = threadIdx.x;
    int w = t >> 6, lane = t & 63, g = lane >> 4, r = lane & 15;
    long n0 = (long)blockIdx.x * FPB;

    // ---- this wave's B slice (jt = w): 7 uint4, loaded once (L2/L3-hot) ----
    uint4 bfrag[NKC];
    {
        const uint4* Bg = (const uint4*)(ws + WS_B);
        #pragma unroll
        for (int kc = 0; kc < NKC; kc++) bfrag[kc] = Bg[(w * NKC + kc) * 64 + lane];
    }
    int j = w * 16 + r;
    float w2j = (j < HDIM) ? W2[j] : 0.f;
    float b1j = (j < HDIM) ? b1[j] : 0.f;

    // ---- stage: compute z from coalesced fe reads, write bf16 tile ----
    for (int e4 = t; e4 < FPB * 25; e4 += NTHREADS) {
        int row = e4 / 25, c4 = e4 % 25;
        float4 f = ((const float4*)(fe + n0 * HDIM))[e4];
        float4 o = *(const float4*)(oc + c4 * 4);
        float4 mm = *(const float4*)(mvec + c4 * 4);
        uint2 z0, z1;
        z0.x = (unsigned)f2bf(fabsf(f.x - o.x)) | ((unsigned)f2bf(fabsf(f.y - o.y)) << 16);
        z0.y = (unsigned)f2bf(fabsf(f.z - o.z)) | ((unsigned)f2bf(fabsf(f.w - o.w)) << 16);
        z1.x = (unsigned)f2bf(fabsf(f.x - mm.x)) | ((unsigned)f2bf(fabsf(f.y - mm.y)) << 16);
        z1.y = (unsigned)f2bf(fabsf(f.z - mm.z)) | ((unsigned)f2bf(fabsf(f.w - mm.w)) << 16);
        unsigned short* zp = ztile + row * ZSTRIDE;
        *(uint2*)(zp + c4 * 4)       = z0;   // k = c4*4 .. +3
        *(uint2*)(zp + 104 + c4 * 4) = z1;   // k = 104 + c4*4 .. +3
    }
    // zero pads: cols 100..103, 204..207, 208..231 (keep dead lanes finite)
    for (int i = t; i < FPB * 8; i += NTHREADS) {
        int row = i >> 3, q = i & 7;
        int col = (q == 0) ? 100 : (q == 1) ? 204 : (208 + (q - 2) * 4);
        *(uint2*)(ztile + row * ZSTRIDE + col) = make_uint2(0u, 0u);
    }
    __syncthreads();

    // ---- GEMM: 8 fact-tiles of 16; pure ds_read_b128 + MFMA, no inner barriers ----
    #pragma unroll
    for (int tile = 0; tile < FPB / 16; tile++) {
        int row = tile * 16 + r;
        const unsigned short* zr = ztile + row * ZSTRIDE;
        f32x4 acc = {0, 0, 0, 0};
        #pragma unroll
        for (int kc = 0; kc < NKC; kc++) {
            uint4 zv = *(const uint4*)(zr + kc * 32 + g * 8);
            acc = __builtin_amdgcn_mfma_f32_16x16x32_bf16(
                __builtin_bit_cast(short8, zv),
                __builtin_bit_cast(short8, bfrag[kc]), acc, 0, 0, 0);
        }
        #pragma unroll
        for (int q = 0; q < 4; q++) {
            float v = tanh_fast(acc[q] + b1j) * w2j;
            v += __shfl_xor(v, 1); v += __shfl_xor(v, 2);
            v += __shfl_xor(v, 4); v += __shfl_xor(v, 8);
            if (r == 0) gvp[w][tile * 16 + g * 4 + q] = v;
        }
    }
    __syncthreads();

    // ---- logits -> exp (b2 dropped: softmax-invariant; |logit| <~ 8) ----
    float e = 0.f;
    if (t < FPB) {
        float l = gvp[0][t];
        #pragma unroll
        for (int jj = 1; jj < NJT; jj++) l += gvp[jj][t];
        e = __expf(l);
        wls[t] = e;
    }
    float s = e;
    #pragma unroll
    for (int off = 32; off; off >>= 1) s += __shfl_down(s, off);
    if (lane == 0 && t < FPB) sred[t >> 6] = s;
    __syncthreads();
    if (t == 0) ws[WS_SP + blockIdx.x] = sred[0] + sred[1];

    // ---- pooling: re-read fe (just streamed -> L2-hot), 400 threads ----
    if (t < 400) {
        int sl = t / HDIM, k = t % HDIM;
        const float* fp = fe + (n0 + sl * 32) * HDIM + k;
        const float* wp = wls + sl * 32;
        float c = 0.f;
        #pragma unroll 4
        for (int n = 0; n < 32; n++) c = fmaf(wp[n], fp[n * HDIM], c);
        poolbuf[sl][k] = c;
    }
    __syncthreads();
    if (t < HDIM) {
        float c = poolbuf[0][t] + poolbuf[1][t] + poolbuf[2][t] + poolbuf[3][t];
        ws[WS_PC + (long)blockIdx.x * HDIM + t] = c;
    }
}

// Combine per-block partials, normalize, gated update. One block.
__global__ __launch_bounds__(1024) void k_final(
        const float* __restrict__ mvec,
        const float* __restrict__ oc,
        const float* __restrict__ W3,
        const float* __restrict__ b3,
        const float* __restrict__ ws,
        float* __restrict__ out) {
    __shared__ float sred[16];
    __shared__ float csl[1000];
    __shared__ float vv[300];
    __shared__ float Sval;
    int t = threadIdx.x;
    int w = t >> 6, lane = t & 63;

    float s = ws[WS_SP + t] + ws[WS_SP + 1024 + t];
    #pragma unroll
    for (int off = 32; off; off >>= 1) s += __shfl_down(s, off);
    if (lane == 0) sred[w] = s;

    if (t < 1000) {
        int sl = t / 100, h = t % 100;
        float a = 0.f;
        #pragma unroll 4
        for (int b = sl; b < NBLK; b += 10) a += ws[WS_PC + (long)b * HDIM + h];
        csl[t] = a;
    }
    __syncthreads();
    if (t == 0) {
        float a = 0.f;
        #pragma unroll
        for (int i = 0; i < 16; i++) a += sred[i];
        Sval = a;
    }
    __syncthreads();
    if (t < HDIM) {
        float c = 0.f;
        #pragma unroll
        for (int sl = 0; sl < 10; sl++) c += csl[sl * 100 + t];
        vv[t] = mvec[t];
        vv[HDIM + t] = c / Sval;
        vv[2 * HDIM + t] = oc[t];
    }
    __syncthreads();
    if (t < HDIM) {
        float a = b3[t];
        const float* wr = W3 + t * 3 * HDIM;
        #pragma unroll 4
        for (int k = 0; k < 3 * HDIM; k++) a = fmaf(wr[k], vv[k], a);
        out[t] = fmaxf(a, 0.f);
    }
}

extern "C" void kernel_launch(void* const* d_in, const int* in_sizes, int n_in,
                              void* d_out, int out_size, void* d_ws, size_t ws_size,
                              hipStream_t stream) {
    const float* mvec = (const float*)d_in[0];
    const float* oh   = (const float*)d_in[1];
    const float* fe   = (const float*)d_in[2];
    const float* W1   = (const float*)d_in[3];
    const float* b1   = (const float*)d_in[4];
    const float* W2   = (const float*)d_in[5];
    const float* W3   = (const float*)d_in[7];
    const float* b3   = (const float*)d_in[8];
    float* ws  = (float*)d_ws;
    float* out = (float*)d_out;

    k_prep_b<<<13, 256, 0, stream>>>(W1, ws);
    k_logits<<<NBLK, NTHREADS, 0, stream>>>(fe, oh, mvec, b1, W2, ws);
    k_final<<<1, 1024, 0, stream>>>(mvec, oh, W3, b3, ws, out);
}